// Round 1
// baseline (770.867 us; speedup 1.0000x reference)
//
#include <hip/hip_runtime.h>

#define BB 16
#define NN 2048
#define DD 64
#define MC 128
#define NCH (NN / MC)   // 16 chunks
#define TM 8            // rows per block

// ---------------------------------------------------------------------------
// prep: node1 = emb @ w1^T + b1 ; node2 = emb @ w2^T + b2   (into ws)
// ---------------------------------------------------------------------------
__global__ __launch_bounds__(256) void prep_nodes(
    const float* __restrict__ emb, const float* __restrict__ w1w,
    const float* __restrict__ w1b, const float* __restrict__ w2w,
    const float* __restrict__ w2b, float* __restrict__ ws)
{
  __shared__ float wl[2][DD][DD];   // 32 KiB: both weight matrices
  int t = threadIdx.x;
  for (int i = t; i < DD * DD; i += 256) {
    wl[0][i >> 6][i & 63] = w1w[i];
    wl[1][i >> 6][i & 63] = w2w[i];
  }
  __syncthreads();
  int g = blockIdx.x * 256 + t;          // 0 .. 2*NN*DD-1
  int which = (g >= NN * DD) ? 1 : 0;
  int idx = which ? g - NN * DD : g;
  int n = idx >> 6, d = idx & 63;
  const float* e = emb + (size_t)n * DD;
  float s = which ? w2b[d] : w1b[d];
  #pragma unroll
  for (int k = 0; k < DD; ++k) s += e[k] * wl[which][d][k];
  ws[g] = s;   // node1 at [0, NN*DD), node2 at [NN*DD, 2*NN*DD)
}

// ---------------------------------------------------------------------------
// prep: v[b,n] = x[b,n,:] . wp + wp_b
// ---------------------------------------------------------------------------
__global__ __launch_bounds__(256) void prep_v(
    const float* __restrict__ x, const float* __restrict__ wpw,
    const float* __restrict__ wpb, float* __restrict__ v)
{
  int g = blockIdx.x * 256 + threadIdx.x;   // b*NN + n
  const float* xr = x + (size_t)g * DD;
  float s = wpb[0];
  #pragma unroll
  for (int kq = 0; kq < DD / 4; ++kq) {
    float4 q = *(const float4*)&xr[kq * 4];
    float4 w = *(const float4*)&wpw[kq * 4];
    s += q.x * w.x + q.y * w.y + q.z * w.z + q.w * w.w;
  }
  v[g] = s;
}

// ---------------------------------------------------------------------------
// big-ws path: adj_base = relu(node1 @ node2^T)  -> ws  (16 MiB)
// block: 8 rows x 2048 cols, cols staged k-major in LDS (pad +1)
// ---------------------------------------------------------------------------
__global__ __launch_bounds__(256) void base_kernel(
    const float* __restrict__ node1, const float* __restrict__ node2,
    float* __restrict__ base)
{
  __shared__ float n1r[TM][DD];
  __shared__ float colbuf[DD][MC + 1];
  int t = threadIdx.x;
  int n0 = blockIdx.x * TM;
  for (int i = t; i < TM * DD; i += 256)
    n1r[i >> 6][i & 63] = node1[(size_t)n0 * DD + i];
  int mloc = t & (MC - 1);
  int r0 = (t >> 7) * 4;
  for (int c = 0; c < NCH; ++c) {
    __syncthreads();
    #pragma unroll
    for (int i = 0; i < 8; ++i) {           // 128 cols * 64 k = 2048 float4
      int f = i * 256 + t;
      int mm = f >> 4, kq = f & 15;
      float4 q = *(const float4*)&node2[(size_t)(c * MC + mm) * DD + kq * 4];
      colbuf[kq * 4 + 0][mm] = q.x; colbuf[kq * 4 + 1][mm] = q.y;
      colbuf[kq * 4 + 2][mm] = q.z; colbuf[kq * 4 + 3][mm] = q.w;
    }
    __syncthreads();
    float acc[4] = {0.f, 0.f, 0.f, 0.f};
    #pragma unroll
    for (int kb = 0; kb < 16; ++kb) {
      float ra[4][4];
      #pragma unroll
      for (int r = 0; r < 4; ++r) {
        float4 q = *(const float4*)&n1r[r0 + r][kb * 4];
        ra[r][0] = q.x; ra[r][1] = q.y; ra[r][2] = q.z; ra[r][3] = q.w;
      }
      #pragma unroll
      for (int kk = 0; kk < 4; ++kk) {
        float cv = colbuf[kb * 4 + kk][mloc];
        #pragma unroll
        for (int r = 0; r < 4; ++r) acc[r] += ra[r][kk] * cv;
      }
    }
    #pragma unroll
    for (int r = 0; r < 4; ++r)
      base[(size_t)(n0 + r0 + r) * NN + c * MC + mloc] = fmaxf(acc[r], 0.f);
  }
}

// ---------------------------------------------------------------------------
// fused main: logits -> softmax -> out, full row in registers.
// USEBASE: read precomputed adj_base; else recompute relu(n1.n2) per block.
// ---------------------------------------------------------------------------
template <bool USEBASE>
__global__ __launch_bounds__(256) void fused_kernel(
    const float* __restrict__ x, const float* __restrict__ node1,
    const float* __restrict__ node2, const float* __restrict__ vv,
    const float* __restrict__ base, float* __restrict__ out)
{
  __shared__ float xr[TM][DD];
  __shared__ float n1r[TM][DD];
  __shared__ float colbuf[2][DD / 2][MC + 1];  // contiguous == [64][MC+1]
  __shared__ float redm[4][4];
  __shared__ float reds[4][4];

  int t = threadIdx.x;
  int b = blockIdx.y;
  int n0 = blockIdx.x * TM;
  int mloc = t & (MC - 1);
  int grp = t >> 7;        // 0: rows 0-3 (waves 0,1), 1: rows 4-7 (waves 2,3)
  int r0 = grp * 4;

  for (int i = t; i < TM * DD; i += 256) {
    xr[i >> 6][i & 63] = x[((size_t)b * NN + n0) * DD + i];
    if (!USEBASE) n1r[i >> 6][i & 63] = node1[(size_t)n0 * DD + i];
  }
  float vrow[4];
  #pragma unroll
  for (int r = 0; r < 4; ++r) vrow[r] = vv[b * NN + n0 + r0 + r];

  float acc[4][NCH];   // 64 logits per thread: 4 rows x 16 chunk-cols

  #pragma unroll
  for (int c = 0; c < NCH; ++c) {
    float dacc[4] = {0.f, 0.f, 0.f, 0.f};
    float bacc[4] = {0.f, 0.f, 0.f, 0.f};
    if (USEBASE) {
      __syncthreads();
      #pragma unroll
      for (int i = 0; i < 8; ++i) {
        int f = i * 256 + t;
        int mm = f >> 4, kq = f & 15;
        float4 q = *(const float4*)&x[((size_t)b * NN + c * MC + mm) * DD + kq * 4];
        int k = kq * 4;
        colbuf[k >> 5][(k + 0) & 31][mm] = q.x;
        colbuf[k >> 5][(k + 1) & 31][mm] = q.y;
        colbuf[k >> 5][(k + 2) & 31][mm] = q.z;
        colbuf[k >> 5][(k + 3) & 31][mm] = q.w;
      }
      __syncthreads();
      #pragma unroll
      for (int kb = 0; kb < 16; ++kb) {
        float ra[4][4];
        #pragma unroll
        for (int r = 0; r < 4; ++r) {
          float4 q = *(const float4*)&xr[r0 + r][kb * 4];
          ra[r][0] = q.x; ra[r][1] = q.y; ra[r][2] = q.z; ra[r][3] = q.w;
        }
        #pragma unroll
        for (int kk = 0; kk < 4; ++kk) {
          int k = kb * 4 + kk;
          float cv = colbuf[k >> 5][k & 31][mloc];
          #pragma unroll
          for (int r = 0; r < 4; ++r) dacc[r] += ra[r][kk] * cv;
        }
      }
    } else {
      // small-ws fallback: recompute base dot; K split in halves to fit LDS
      #pragma unroll
      for (int h = 0; h < 2; ++h) {
        __syncthreads();
        #pragma unroll
        for (int i = 0; i < 8; ++i) {
          int f = i * 256 + t;          // first 1024 f4: x, next 1024: node2
          int arr = f >> 10;
          int ff = f & 1023;
          int mm = ff >> 3, kq = ff & 7;
          const float* src = arr
              ? node2 + (size_t)(c * MC + mm) * DD + h * 32 + kq * 4
              : x + ((size_t)b * NN + c * MC + mm) * DD + h * 32 + kq * 4;
          float4 q = *(const float4*)src;
          colbuf[arr][kq * 4 + 0][mm] = q.x;
          colbuf[arr][kq * 4 + 1][mm] = q.y;
          colbuf[arr][kq * 4 + 2][mm] = q.z;
          colbuf[arr][kq * 4 + 3][mm] = q.w;
        }
        __syncthreads();
        #pragma unroll
        for (int kb = 0; kb < 8; ++kb) {
          float ra[4][4], rb[4][4];
          #pragma unroll
          for (int r = 0; r < 4; ++r) {
            float4 qx = *(const float4*)&xr[r0 + r][h * 32 + kb * 4];
            ra[r][0] = qx.x; ra[r][1] = qx.y; ra[r][2] = qx.z; ra[r][3] = qx.w;
            float4 qn = *(const float4*)&n1r[r0 + r][h * 32 + kb * 4];
            rb[r][0] = qn.x; rb[r][1] = qn.y; rb[r][2] = qn.z; rb[r][3] = qn.w;
          }
          #pragma unroll
          for (int kk = 0; kk < 4; ++kk) {
            float cx = colbuf[0][kb * 4 + kk][mloc];
            float cn = colbuf[1][kb * 4 + kk][mloc];
            #pragma unroll
            for (int r = 0; r < 4; ++r) {
              dacc[r] += ra[r][kk] * cx;
              bacc[r] += rb[r][kk] * cn;
            }
          }
        }
      }
    }
    float vc = vv[b * NN + c * MC + mloc];
    #pragma unroll
    for (int r = 0; r < 4; ++r) {
      float lg = dacc[r] + vrow[r] - vc;
      if (USEBASE)
        lg += base[(size_t)(n0 + r0 + r) * NN + c * MC + mloc];
      else
        lg += fmaxf(bacc[r], 0.f);
      acc[r][c] = lg;
    }
  }

  // ---- softmax over the 2048-wide row (4 rows per thread-group) ----
  float pm[4];
  #pragma unroll
  for (int r = 0; r < 4; ++r) {
    float m = acc[r][0];
    #pragma unroll
    for (int c = 1; c < NCH; ++c) m = fmaxf(m, acc[r][c]);
    #pragma unroll
    for (int off = 32; off >= 1; off >>= 1)
      m = fmaxf(m, __shfl_xor(m, off, 64));
    pm[r] = m;
  }
  int w = t >> 6;
  if ((t & 63) == 0) {
    #pragma unroll
    for (int r = 0; r < 4; ++r) redm[w][r] = pm[r];
  }
  __syncthreads();
  float mrow[4], ps[4];
  #pragma unroll
  for (int r = 0; r < 4; ++r) {
    mrow[r] = fmaxf(redm[grp * 2][r], redm[grp * 2 + 1][r]);
    ps[r] = 0.f;
  }
  #pragma unroll
  for (int c = 0; c < NCH; ++c) {
    #pragma unroll
    for (int r = 0; r < 4; ++r) {
      float e = __expf(acc[r][c] - mrow[r]);
      acc[r][c] = e;
      ps[r] += e;
    }
  }
  #pragma unroll
  for (int r = 0; r < 4; ++r) {
    #pragma unroll
    for (int off = 32; off >= 1; off >>= 1)
      ps[r] += __shfl_xor(ps[r], off, 64);
  }
  if ((t & 63) == 0) {
    #pragma unroll
    for (int r = 0; r < 4; ++r) reds[w][r] = ps[r];
  }
  __syncthreads();
  float inv[4];
  #pragma unroll
  for (int r = 0; r < 4; ++r)
    inv[r] = 1.f / (reds[grp * 2][r] + reds[grp * 2 + 1][r]);

  #pragma unroll
  for (int c = 0; c < NCH; ++c) {
    #pragma unroll
    for (int r = 0; r < 4; ++r)
      out[((size_t)b * NN + n0 + r0 + r) * NN + c * MC + mloc] = acc[r][c] * inv[r];
  }
}

// ---------------------------------------------------------------------------
extern "C" void kernel_launch(void* const* d_in, const int* in_sizes, int n_in,
                              void* d_out, int out_size, void* d_ws, size_t ws_size,
                              hipStream_t stream)
{
  const float* x   = (const float*)d_in[0];
  const float* emb = (const float*)d_in[1];
  const float* w1w = (const float*)d_in[2];
  const float* w1b = (const float*)d_in[3];
  const float* w2w = (const float*)d_in[4];
  const float* w2b = (const float*)d_in[5];
  const float* wpw = (const float*)d_in[6];
  const float* wpb = (const float*)d_in[7];
  float* out = (float*)d_out;

  float* wsf   = (float*)d_ws;
  float* node1 = wsf;
  float* node2 = wsf + (size_t)NN * DD;
  float* v     = wsf + (size_t)2 * NN * DD;
  float* base  = wsf + (size_t)2 * NN * DD + (size_t)BB * NN;

  size_t need_big = ((size_t)2 * NN * DD + (size_t)BB * NN + (size_t)NN * NN) * sizeof(float);
  bool big = ws_size >= need_big;

  prep_nodes<<<2 * NN * DD / 256, 256, 0, stream>>>(emb, w1w, w1b, w2w, w2b, wsf);
  prep_v<<<BB * NN / 256, 256, 0, stream>>>(x, wpw, wpb, v);

  dim3 grid(NN / TM, BB);
  if (big) {
    base_kernel<<<NN / TM, 256, 0, stream>>>(node1, node2, base);
    fused_kernel<true><<<grid, 256, 0, stream>>>(x, node1, node2, v, base, out);
  } else {
    fused_kernel<false><<<grid, 256, 0, stream>>>(x, node1, node2, v, base, out);
  }
}

// Round 2
// 505.204 us; speedup vs baseline: 1.5259x; 1.5259x over previous
//
#include <hip/hip_runtime.h>

#define BB 16
#define NN 2048
#define DD 64
#define MC 128
#define NCH (NN / MC)
#define TM 8

typedef __bf16 bf16x8 __attribute__((ext_vector_type(8)));
typedef float f32x4 __attribute__((ext_vector_type(4)));
typedef int i32x4 __attribute__((ext_vector_type(4)));

#define MFMA16 __builtin_amdgcn_mfma_f32_16x16x32_bf16

__device__ inline unsigned short f2bf(float f) {
  unsigned u = __float_as_uint(f);
  unsigned r = u + 0x7FFFu + ((u >> 16) & 1u);
  return (unsigned short)(r >> 16);
}
__device__ inline float bf2f(unsigned short h) {
  return __uint_as_float(((unsigned)h) << 16);
}
__device__ inline bf16x8 ldfrag(const unsigned short* p) {
  i32x4 v = *reinterpret_cast<const i32x4*>(p);
  return __builtin_bit_cast(bf16x8, v);
}

// ---------------------------------------------------------------------------
// prep: node1/node2 fp32 (for fallback) + bf16 hi/lo splits (for MFMA path)
// ---------------------------------------------------------------------------
__global__ __launch_bounds__(256) void prep_nodes(
    const float* __restrict__ emb, const float* __restrict__ w1w,
    const float* __restrict__ w1b, const float* __restrict__ w2w,
    const float* __restrict__ w2b, float* __restrict__ n1f,
    float* __restrict__ n2f, unsigned short* __restrict__ n1hi,
    unsigned short* __restrict__ n1lo, unsigned short* __restrict__ n2hi,
    unsigned short* __restrict__ n2lo, int wantbf)
{
  __shared__ float wl[2][DD][DD];
  int t = threadIdx.x;
  for (int i = t; i < DD * DD; i += 256) {
    wl[0][i >> 6][i & 63] = w1w[i];
    wl[1][i >> 6][i & 63] = w2w[i];
  }
  __syncthreads();
  int g = blockIdx.x * 256 + t;
  int which = (g >= NN * DD) ? 1 : 0;
  int idx = which ? g - NN * DD : g;
  int n = idx >> 6, d = idx & 63;
  const float* e = emb + (size_t)n * DD;
  float s = which ? w2b[d] : w1b[d];
  #pragma unroll
  for (int k = 0; k < DD; ++k) s += e[k] * wl[which][d][k];
  (which ? n2f : n1f)[idx] = s;
  if (wantbf) {
    unsigned short hi = f2bf(s);
    unsigned short lo = f2bf(s - bf2f(hi));
    (which ? n2hi : n1hi)[idx] = hi;
    (which ? n2lo : n1lo)[idx] = lo;
  }
}

// ---------------------------------------------------------------------------
// prep: x -> bf16 hi/lo split arrays
// ---------------------------------------------------------------------------
__global__ __launch_bounds__(256) void prep_x(
    const float* __restrict__ x, unsigned short* __restrict__ xhi,
    unsigned short* __restrict__ xlo)
{
  int g = blockIdx.x * 256 + threadIdx.x;
  int e0 = g * 4;
  float4 xx = *(const float4*)&x[e0];
  ushort4 hi, lo;
  hi.x = f2bf(xx.x); lo.x = f2bf(xx.x - bf2f(hi.x));
  hi.y = f2bf(xx.y); lo.y = f2bf(xx.y - bf2f(hi.y));
  hi.z = f2bf(xx.z); lo.z = f2bf(xx.z - bf2f(hi.z));
  hi.w = f2bf(xx.w); lo.w = f2bf(xx.w - bf2f(hi.w));
  *(ushort4*)&xhi[e0] = hi;
  *(ushort4*)&xlo[e0] = lo;
}

// ---------------------------------------------------------------------------
// prep: v[b,n] = x[b,n,:] . wp + wp_b
// ---------------------------------------------------------------------------
__global__ __launch_bounds__(256) void prep_v(
    const float* __restrict__ x, const float* __restrict__ wpw,
    const float* __restrict__ wpb, float* __restrict__ v)
{
  int g = blockIdx.x * 256 + threadIdx.x;
  const float* xr = x + (size_t)g * DD;
  float s = wpb[0];
  #pragma unroll
  for (int kq = 0; kq < DD / 4; ++kq) {
    float4 q = *(const float4*)&xr[kq * 4];
    float4 w = *(const float4*)&wpw[kq * 4];
    s += q.x * w.x + q.y * w.y + q.z * w.z + q.w * w.w;
  }
  v[g] = s;
}

// ---------------------------------------------------------------------------
// base = relu(n1 @ n2^T) via split-bf16 MFMA. 128 blocks x 16 rows.
// ---------------------------------------------------------------------------
__global__ __launch_bounds__(256, 2) void base_mfma(
    const unsigned short* __restrict__ n1hi, const unsigned short* __restrict__ n1lo,
    const unsigned short* __restrict__ n2hi, const unsigned short* __restrict__ n2lo,
    float* __restrict__ base)
{
  int t = threadIdx.x, lane = t & 63, w = t >> 6;
  int q = lane >> 4, m = lane & 15;
  int n0 = blockIdx.x * 16, cw = w * 512;
  int aidx = (n0 + m) * DD + q * 8;
  bf16x8 ah0 = ldfrag(n1hi + aidx), ah1 = ldfrag(n1hi + aidx + 32);
  bf16x8 al0 = ldfrag(n1lo + aidx), al1 = ldfrag(n1lo + aidx + 32);
  #pragma unroll
  for (int tt = 0; tt < 32; ++tt) {
    int c = cw + tt * 16 + m;
    int bidx = c * DD + q * 8;
    bf16x8 bh0 = ldfrag(n2hi + bidx), bh1 = ldfrag(n2hi + bidx + 32);
    bf16x8 bl0 = ldfrag(n2lo + bidx), bl1 = ldfrag(n2lo + bidx + 32);
    f32x4 acc = {0.f, 0.f, 0.f, 0.f};
    acc = MFMA16(ah0, bh0, acc, 0, 0, 0);
    acc = MFMA16(ah1, bh1, acc, 0, 0, 0);
    acc = MFMA16(ah0, bl0, acc, 0, 0, 0);
    acc = MFMA16(ah1, bl1, acc, 0, 0, 0);
    acc = MFMA16(al0, bh0, acc, 0, 0, 0);
    acc = MFMA16(al1, bh1, acc, 0, 0, 0);
    #pragma unroll
    for (int r = 0; r < 4; ++r)
      base[(size_t)(n0 + q * 4 + r) * NN + cw + tt * 16 + m] = fmaxf(acc[r], 0.f);
  }
}

// ---------------------------------------------------------------------------
// fused: dyn (split-bf16 MFMA) + base + (v_n - v_m) -> softmax -> out
// grid (128 row-blocks, 16 batches), 256 thr. Wave owns 16 rows x 512 cols.
// C/D layout: col = lane&15, row = (lane>>4)*4 + reg.
// ---------------------------------------------------------------------------
__global__ __launch_bounds__(256, 2) void fused_mfma(
    const unsigned short* __restrict__ xhi, const unsigned short* __restrict__ xlo,
    const float* __restrict__ base, const float* __restrict__ vv,
    float* __restrict__ out)
{
  __shared__ float redm[4][16];
  __shared__ float reds[4][16];
  int t = threadIdx.x, lane = t & 63, w = t >> 6;
  int q = lane >> 4, m = lane & 15;
  int b = blockIdx.y, n0 = blockIdx.x * 16, cw = w * 512;
  size_t xb = (size_t)b * NN * DD;

  int aoff = (n0 + m) * DD + q * 8;
  bf16x8 ah0 = ldfrag(xhi + xb + aoff), ah1 = ldfrag(xhi + xb + aoff + 32);
  bf16x8 al0 = ldfrag(xlo + xb + aoff), al1 = ldfrag(xlo + xb + aoff + 32);

  f32x4 acc[32];
  #pragma unroll
  for (int tt = 0; tt < 32; ++tt) {
    int c = cw + tt * 16 + m;
    size_t bidx = xb + (size_t)c * DD + q * 8;
    bf16x8 bh0 = ldfrag(xhi + bidx), bh1 = ldfrag(xhi + bidx + 32);
    bf16x8 bl0 = ldfrag(xlo + bidx), bl1 = ldfrag(xlo + bidx + 32);
    f32x4 a = {0.f, 0.f, 0.f, 0.f};
    a = MFMA16(ah0, bh0, a, 0, 0, 0);
    a = MFMA16(ah1, bh1, a, 0, 0, 0);
    a = MFMA16(ah0, bl0, a, 0, 0, 0);
    a = MFMA16(ah1, bl1, a, 0, 0, 0);
    a = MFMA16(al0, bh0, a, 0, 0, 0);
    a = MFMA16(al1, bh1, a, 0, 0, 0);
    acc[tt] = a;
  }

  // add base + v_row - v_col
  float vrow[4];
  #pragma unroll
  for (int r = 0; r < 4; ++r) vrow[r] = vv[b * NN + n0 + q * 4 + r];
  #pragma unroll
  for (int tt = 0; tt < 32; ++tt) {
    int c = cw + tt * 16 + m;
    float vc = vv[b * NN + c];
    #pragma unroll
    for (int r = 0; r < 4; ++r)
      acc[tt][r] += base[(size_t)(n0 + q * 4 + r) * NN + c] + vrow[r] - vc;
  }

  // row max: per-lane over tiles, quad shuffle (lanes share rows within quad),
  // then cross-wave via LDS
  float mx[4];
  #pragma unroll
  for (int r = 0; r < 4; ++r) mx[r] = acc[0][r];
  #pragma unroll
  for (int tt = 1; tt < 32; ++tt)
    #pragma unroll
    for (int r = 0; r < 4; ++r) mx[r] = fmaxf(mx[r], acc[tt][r]);
  #pragma unroll
  for (int off = 8; off >= 1; off >>= 1)
    #pragma unroll
    for (int r = 0; r < 4; ++r) mx[r] = fmaxf(mx[r], __shfl_xor(mx[r], off, 64));
  if (m == 0) {
    #pragma unroll
    for (int r = 0; r < 4; ++r) redm[w][q * 4 + r] = mx[r];
  }
  __syncthreads();
  float mrow[4], sm[4];
  #pragma unroll
  for (int r = 0; r < 4; ++r) {
    int rr = q * 4 + r;
    mrow[r] = fmaxf(fmaxf(redm[0][rr], redm[1][rr]), fmaxf(redm[2][rr], redm[3][rr]));
    sm[r] = 0.f;
  }
  #pragma unroll
  for (int tt = 0; tt < 32; ++tt)
    #pragma unroll
    for (int r = 0; r < 4; ++r) {
      float e = __expf(acc[tt][r] - mrow[r]);
      acc[tt][r] = e;
      sm[r] += e;
    }
  #pragma unroll
  for (int off = 8; off >= 1; off >>= 1)
    #pragma unroll
    for (int r = 0; r < 4; ++r) sm[r] += __shfl_xor(sm[r], off, 64);
  if (m == 0) {
    #pragma unroll
    for (int r = 0; r < 4; ++r) reds[w][q * 4 + r] = sm[r];
  }
  __syncthreads();
  float inv[4];
  #pragma unroll
  for (int r = 0; r < 4; ++r) {
    int rr = q * 4 + r;
    inv[r] = 1.f / (reds[0][rr] + reds[1][rr] + reds[2][rr] + reds[3][rr]);
  }
  #pragma unroll
  for (int tt = 0; tt < 32; ++tt) {
    int c = cw + tt * 16 + m;
    #pragma unroll
    for (int r = 0; r < 4; ++r)
      out[((size_t)b * NN + n0 + q * 4 + r) * NN + c] = acc[tt][r] * inv[r];
  }
}

// ---------------------------------------------------------------------------
// small-ws fallback (R1 VALU path, recomputes base dot per block)
// ---------------------------------------------------------------------------
__global__ __launch_bounds__(256) void fused_fallback(
    const float* __restrict__ x, const float* __restrict__ node1,
    const float* __restrict__ node2, const float* __restrict__ vv,
    float* __restrict__ out)
{
  __shared__ float xr[TM][DD];
  __shared__ float n1r[TM][DD];
  __shared__ float colbuf[2][DD / 2][MC + 1];
  __shared__ float redm[4][4];
  __shared__ float reds[4][4];

  int t = threadIdx.x;
  int b = blockIdx.y;
  int n0 = blockIdx.x * TM;
  int mloc = t & (MC - 1);
  int grp = t >> 7;
  int r0 = grp * 4;

  for (int i = t; i < TM * DD; i += 256) {
    xr[i >> 6][i & 63] = x[((size_t)b * NN + n0) * DD + i];
    n1r[i >> 6][i & 63] = node1[(size_t)n0 * DD + i];
  }
  float vrow[4];
  #pragma unroll
  for (int r = 0; r < 4; ++r) vrow[r] = vv[b * NN + n0 + r0 + r];

  float acc[4][NCH];

  #pragma unroll
  for (int c = 0; c < NCH; ++c) {
    float dacc[4] = {0.f, 0.f, 0.f, 0.f};
    float bacc[4] = {0.f, 0.f, 0.f, 0.f};
    #pragma unroll
    for (int h = 0; h < 2; ++h) {
      __syncthreads();
      #pragma unroll
      for (int i = 0; i < 8; ++i) {
        int f = i * 256 + t;
        int arr = f >> 10;
        int ff = f & 1023;
        int mm = ff >> 3, kq = ff & 7;
        const float* src = arr
            ? node2 + (size_t)(c * MC + mm) * DD + h * 32 + kq * 4
            : x + ((size_t)b * NN + c * MC + mm) * DD + h * 32 + kq * 4;
        float4 qv = *(const float4*)src;
        colbuf[arr][kq * 4 + 0][mm] = qv.x;
        colbuf[arr][kq * 4 + 1][mm] = qv.y;
        colbuf[arr][kq * 4 + 2][mm] = qv.z;
        colbuf[arr][kq * 4 + 3][mm] = qv.w;
      }
      __syncthreads();
      #pragma unroll
      for (int kb = 0; kb < 8; ++kb) {
        float ra[4][4], rb[4][4];
        #pragma unroll
        for (int r = 0; r < 4; ++r) {
          float4 qx = *(const float4*)&xr[r0 + r][h * 32 + kb * 4];
          ra[r][0] = qx.x; ra[r][1] = qx.y; ra[r][2] = qx.z; ra[r][3] = qx.w;
          float4 qn = *(const float4*)&n1r[r0 + r][h * 32 + kb * 4];
          rb[r][0] = qn.x; rb[r][1] = qn.y; rb[r][2] = qn.z; rb[r][3] = qn.w;
        }
        #pragma unroll
        for (int kk = 0; kk < 4; ++kk) {
          float cx = colbuf[0][kb * 4 + kk][mloc];
          float cn = colbuf[1][kb * 4 + kk][mloc];
          #pragma unroll
          for (int r = 0; r < 4; ++r) {
            dacc[r] += ra[r][kk] * cx;
            bacc[r] += rb[r][kk] * cn;
          }
        }
      }
    }
    float vc = vv[b * NN + c * MC + mloc];
    #pragma unroll
    for (int r = 0; r < 4; ++r)
      acc[r][c] = dacc[r] + vrow[r] - vc + fmaxf(bacc[r], 0.f);
  }

  float pm[4];
  #pragma unroll
  for (int r = 0; r < 4; ++r) {
    float mv = acc[r][0];
    #pragma unroll
    for (int c = 1; c < NCH; ++c) mv = fmaxf(mv, acc[r][c]);
    #pragma unroll
    for (int off = 32; off >= 1; off >>= 1)
      mv = fmaxf(mv, __shfl_xor(mv, off, 64));
    pm[r] = mv;
  }
  int w = t >> 6;
  if ((t & 63) == 0) {
    #pragma unroll
    for (int r = 0; r < 4; ++r) redm[w][r] = pm[r];
  }
  __syncthreads();
  float mrow[4], ps[4];
  #pragma unroll
  for (int r = 0; r < 4; ++r) {
    mrow[r] = fmaxf(redm[grp * 2][r], redm[grp * 2 + 1][r]);
    ps[r] = 0.f;
  }
  #pragma unroll
  for (int c = 0; c < NCH; ++c)
    #pragma unroll
    for (int r = 0; r < 4; ++r) {
      float e = __expf(acc[r][c] - mrow[r]);
      acc[r][c] = e;
      ps[r] += e;
    }
  #pragma unroll
  for (int r = 0; r < 4; ++r)
    #pragma unroll
    for (int off = 32; off >= 1; off >>= 1)
      ps[r] += __shfl_xor(ps[r], off, 64);
  if ((t & 63) == 0) {
    #pragma unroll
    for (int r = 0; r < 4; ++r) reds[w][r] = ps[r];
  }
  __syncthreads();
  float inv[4];
  #pragma unroll
  for (int r = 0; r < 4; ++r)
    inv[r] = 1.f / (reds[grp * 2][r] + reds[grp * 2 + 1][r]);
  #pragma unroll
  for (int c = 0; c < NCH; ++c)
    #pragma unroll
    for (int r = 0; r < 4; ++r)
      out[((size_t)b * NN + n0 + r0 + r) * NN + c * MC + mloc] = acc[r][c] * inv[r];
}

// ---------------------------------------------------------------------------
extern "C" void kernel_launch(void* const* d_in, const int* in_sizes, int n_in,
                              void* d_out, int out_size, void* d_ws, size_t ws_size,
                              hipStream_t stream)
{
  const float* x   = (const float*)d_in[0];
  const float* emb = (const float*)d_in[1];
  const float* w1w = (const float*)d_in[2];
  const float* w1b = (const float*)d_in[3];
  const float* w2w = (const float*)d_in[4];
  const float* w2b = (const float*)d_in[5];
  const float* wpw = (const float*)d_in[6];
  const float* wpb = (const float*)d_in[7];
  float* out = (float*)d_out;

  float* wsf   = (float*)d_ws;
  float* node1 = wsf;
  float* node2 = wsf + (size_t)NN * DD;
  float* v     = wsf + (size_t)2 * NN * DD;
  float* base  = wsf + (size_t)2 * NN * DD + (size_t)BB * NN;
  unsigned short* bfb = (unsigned short*)(base + (size_t)NN * NN);
  unsigned short* xhi = bfb;
  unsigned short* xlo = xhi + (size_t)BB * NN * DD;
  unsigned short* n1hi = xlo + (size_t)BB * NN * DD;
  unsigned short* n1lo = n1hi + (size_t)NN * DD;
  unsigned short* n2hi = n1lo + (size_t)NN * DD;
  unsigned short* n2lo = n2hi + (size_t)NN * DD;

  size_t need_mfma = ((size_t)2 * NN * DD + (size_t)BB * NN + (size_t)NN * NN) * 4
                   + ((size_t)2 * BB * NN * DD + (size_t)4 * NN * DD) * 2;
  bool big = ws_size >= need_mfma;

  prep_nodes<<<2 * NN * DD / 256, 256, 0, stream>>>(
      emb, w1w, w1b, w2w, w2b, node1, node2, n1hi, n1lo, n2hi, n2lo, big ? 1 : 0);
  prep_v<<<BB * NN / 256, 256, 0, stream>>>(x, wpw, wpb, v);

  if (big) {
    prep_x<<<BB * NN * DD / 4 / 256, 256, 0, stream>>>(x, xhi, xlo);
    base_mfma<<<NN / 16, 256, 0, stream>>>(n1hi, n1lo, n2hi, n2lo, base);
    dim3 grid(NN / 16, BB);
    fused_mfma<<<grid, 256, 0, stream>>>(xhi, xlo, base, v, out);
  } else {
    dim3 grid(NN / TM, BB);
    fused_fallback<<<grid, 256, 0, stream>>>(x, node1, node2, v, out);
  }
}